// Round 8
// baseline (221.044 us; speedup 1.0000x reference)
//
#include <hip/hip_runtime.h>

typedef __attribute__((ext_vector_type(4))) float f32x4;
typedef __attribute__((ext_vector_type(4))) unsigned int u32x4;
typedef __attribute__((ext_vector_type(8))) unsigned short u16x8;
typedef __attribute__((ext_vector_type(8))) __bf16 bf16x8;

#define DEVFN static __device__ __forceinline__

DEVFN unsigned short f2b(float f) {
  unsigned u = __builtin_bit_cast(unsigned, f);
  u += 0x7fffu + ((u >> 16) & 1u);
  return (unsigned short)(u >> 16);
}
DEVFN float b2f(unsigned short h) {
  unsigned u = ((unsigned)h) << 16;
  return __builtin_bit_cast(float, u);
}
DEVFN float sigf(float x) { return 1.0f / (1.0f + __expf(-x)); }

// ---------------- geometry ----------------
#define CS 264
#define KPAD 2432
#define NTILE 38

// ---------------- workspace layout (bytes) ----------------
#define XP_BYTES (16ull*66*66*CS*2)
#define WT_BYTES (512ull*KPAD*2)       // wt2: fragment-linear packed B
#define W2_BYTES (64ull*512*2)
#define CV_BYTES (65536ull*512*2)
#define PS_BYTES (512ull*256*2*4)
#define XP_OFF 0ull
#define WT_OFF (XP_OFF + XP_BYTES)
#define W2_OFF (WT_OFF + WT_BYTES)
#define CV_OFF (W2_OFF + W2_BYTES)
#define PS_OFF (CV_OFF + CV_BYTES)
#define SB_OFF (PS_OFF + PS_BYTES)

#define GLOAD16(gp, lp) __builtin_amdgcn_global_load_lds( \
    (__attribute__((address_space(1))) void*)(gp),        \
    (__attribute__((address_space(3))) void*)(lp), 16, 0, 0)

#define BAR()  do { __builtin_amdgcn_s_barrier(); __builtin_amdgcn_sched_barrier(0); } while (0)
#define WLG0() do { asm volatile("s_waitcnt lgkmcnt(0)" ::: "memory"); __builtin_amdgcn_sched_barrier(0); } while (0)

// ---------------- merged prep kernel ----------------
// [0,537) zero-border | [537,793) grid ch | [793,5657) pack conv B (fragment-linear) | [5657,5785) head w
__global__ void k_prep(const float* __restrict__ wc, const float* __restrict__ wl,
                       const float* __restrict__ wm, unsigned short* __restrict__ xp,
                       unsigned short* __restrict__ wt2, unsigned short* __restrict__ w2) {
  int bid = blockIdx.x, tid = threadIdx.x;
  if (bid < 537) {
    int idx = bid * 256 + tid;
    if (idx >= 137280) return;
    int cell_i = idx / 33, u = idx - cell_i * 33;
    int b = cell_i / 260, r = cell_i - b * 260;
    int y, x;
    if (r < 66) { y = 0; x = r; }
    else if (r < 132) { y = 65; x = r - 66; }
    else if (r < 196) { y = r - 131; x = 0; }
    else { y = r - 195; x = 65; }
    int cell = (b * 66 + y) * 66 + x;
    *(u32x4*)((unsigned char*)xp + (size_t)cell * (CS * 2) + u * 16) = (u32x4){0u, 0u, 0u, 0u};
  } else if (bid < 793) {
    int pid = (bid - 537) * 256 + tid;
    int b = pid >> 12, pi = pid & 4095, y = pi >> 6, x = pi & 63;
    u16x8 v0 = (u16x8){0, 0, 0, 0, 0, 0, 0, 0};
    v0[0] = f2b((float)x); v0[1] = f2b((float)y);
    *(u16x8*)(xp + ((size_t)((b * 66 + y + 1) * 66 + x + 1)) * CS + 256) = v0;
  } else if (bid < 5657) {
    int idx = (bid - 793) * 256 + tid;   // 512*2432 = 1245184
    int o = idx / KPAD, k = idx - o * KPAD;
    int dy = k / 800, t = k - dy * 800;
    int dx = t / CS, ci = t - dx * CS;
    float v = (dy < 3 && dx < 3 && ci < 258) ? wc[(size_t)(o * 258 + ci) * 9 + dy * 3 + dx] : 0.f;
    // fragment-linear dest: [nt][tau][wn][nf*2+kk][(ko*16+r)*8+e]
    int ntv = o >> 8, o2 = o & 255, wn = o2 >> 6, o3 = o2 & 63, nf = o3 >> 4, r = o3 & 15;
    int tau = k >> 6, k2 = k & 63, kk = k2 >> 5, k3 = k2 & 31, ko = k3 >> 3, e = k3 & 7;
    size_t off = ((size_t)(((ntv * 38 + tau) * 4 + wn) * 8 + nf * 2 + kk)) * 512 + (ko * 16 + r) * 8 + e;
    wt2[off] = f2b(v);
  } else {
    int idx = (bid - 5657) * 256 + tid;
    int o = idx >> 9, k = idx & 511;
    float v = 0.f;
    if (o < 10) v = wl[o * 512 + k];
    else if (o < 58) v = wm[(o - 10) * 512 + k];
    w2[idx] = f2b(v);
  }
}

// input1 (16,256,64,64) f32 -> Xp[b][y+1][x+1][c] bf16 (c<256)
__global__ void k_pack_in(const float* __restrict__ in1, unsigned short* __restrict__ xp) {
  __shared__ float lt[32][65];
  int tid = threadIdx.x;
  int bid = blockIdx.x;
  int cg = bid & 7, y = (bid >> 3) & 63, b = bid >> 9;
  int x = tid & 63, cr = tid >> 6;
#pragma unroll
  for (int i = 0; i < 8; ++i) {
    int cl = i * 4 + cr;
    lt[cl][x] = in1[(((size_t)(b * 256 + cg * 32 + cl) * 64 + y) * 64) + x];
  }
  __syncthreads();
  int xx = tid >> 2, ch = tid & 3;
  u16x8 v;
#pragma unroll
  for (int j = 0; j < 8; ++j) v[j] = f2b(lt[ch * 8 + j][xx]);
  size_t base = ((size_t)((b * 66 + y + 1) * 66 + xx + 1)) * CS + cg * 32 + ch * 8;
  *(u16x8*)(xp + base) = v;
}

// ---------------- conv: 256x256 tile, BK=64; A via 64KB LDS dbuf, B via coalesced global->reg ----------------
// Per tile: top issues ALL VMEM (B(tau+1) regs + both stageA(tau+1) halves -> ~1900cy slack before the
// end-W2 vmcnt(0) drain); 4 MFMA windows hide 4 A ds_reads each (W3 reads NEXT tile's af-lo-k0);
// ONE barrier per tile. 64KB LDS -> 2 blocks/CU co-scheduled.
__global__ __launch_bounds__(512, 2) void k_conv8(const unsigned short* __restrict__ xp,
                                                  const unsigned short* __restrict__ wt2,
                                                  unsigned short* __restrict__ cv,
                                                  float* __restrict__ ps) {
  extern __shared__ char smem[];
  int tid = threadIdx.x, lane = tid & 63, wv = tid >> 6;
  int wm = wv >> 2, wn = wv & 3;
  int bid = blockIdx.x;
  int xcd = bid & 7, j = bid >> 3;
  int nt = j & 1;
  int mt = xcd * 32 + (j >> 1);
  int n0 = nt * 256;
  int pix0 = mt * 256;
  int b = pix0 >> 12, pi0 = pix0 & 4095;

  // ---- A staging constants ----
  int srow = tid >> 3;
  int ug = (tid & 7) ^ (srow & 7);
  unsigned cellB[4];
#pragma unroll
  for (int jj = 0; jj < 4; ++jj) {
    int pi = pi0 + srow + 64 * jj;
    int yy = pi >> 6, xx = pi & 63;
    cellB[jj] = (unsigned)((b * 66 + yy) * 66 + xx) * (CS * 2);
  }

  auto stageA = [&](int tau, int h) {
    int buf = tau & 1;
    unsigned k = (unsigned)tau * 64u + (unsigned)ug * 8u;
    unsigned dy = k / 800u;
    unsigned t = k - dy * 800u;
    unsigned off = dy * (66u * CS * 2u) + t * 2u;
    const unsigned char* g = (const unsigned char*)xp;
    char* l = smem + buf * 32768 + h * 16384;
    GLOAD16(g + cellB[h * 2] + off, l + tid * 16);
    GLOAD16(g + cellB[h * 2 + 1] + off, l + 8192 + tid * 16);
  };

  // ---- fragment read constants ----
  unsigned aoffb[8];
#pragma unroll
  for (int mf = 0; mf < 8; ++mf) aoffb[mf] = (unsigned)(wm * 128 + mf * 16 + (lane & 15)) * 128u;
  int ko = (lane >> 4) & 3, xm = lane & 7;
  unsigned un[2];
#pragma unroll
  for (int kk = 0; kk < 2; ++kk) un[kk] = (unsigned)(((kk * 4 + ko) ^ xm) * 16);

  // B base for this wave: chunks of 1KB, index ((nt*38+tau)*4+wn)*8 + nf*2+kk
  const char* wb = (const char*)wt2 + ((size_t)(nt * 38 * 4 + wn) * 8) * 1024 + (size_t)lane * 16;
  const size_t WTAU = 4 * 8 * 1024;   // byte stride per tau

  f32x4 acc[8][4];
#pragma unroll
  for (int i = 0; i < 8; ++i)
#pragma unroll
    for (int jj = 0; jj < 4; ++jj) acc[i][jj] = (f32x4){0.f, 0.f, 0.f, 0.f};

  bf16x8 af[4][2], bA[4][2], bB[4][2];

  // ---- prologue: stage A(0); load B(0)->bA; drain; pre-read af-lo-k0(0) ----
  stageA(0, 0); stageA(0, 1);
#pragma unroll
  for (int nf = 0; nf < 4; ++nf) {
    bA[nf][0] = *(const bf16x8*)(wb + (nf * 2 + 0) * 1024);
    bA[nf][1] = *(const bf16x8*)(wb + (nf * 2 + 1) * 1024);
  }
  asm volatile("s_waitcnt vmcnt(0)" ::: "memory");
  __builtin_amdgcn_sched_barrier(0);
  BAR();
  {
    const char* base0 = smem;
#pragma unroll
    for (int s = 0; s < 4; ++s) af[s][0] = *(const bf16x8*)(base0 + aoffb[s] + un[0]);
  }

#define MMX(mi, ni, kk, ab, BC) acc[(ab) + (mi)][(ni)] = \
    __builtin_amdgcn_mfma_f32_16x16x32_bf16(af[(mi)][(kk)], BC[(ni)][(kk)], acc[(ab) + (mi)][(ni)], 0, 0, 0)

// steady tile body: top-issues B(tau+1)->BN + stageA(tau+1) both halves; consumes BC; 1 barrier
#define TILE_STEADY(tau, BC, BN)                                                        \
  {                                                                                     \
    const char* base = smem + ((tau) & 1) * 32768;                                      \
    const char* nbase = smem + (((tau) + 1) & 1) * 32768;                               \
    const char* wbn = wb + (size_t)((tau) + 1) * WTAU;                                  \
    /* top: issue ALL next-tile VMEM (buf(tau+1) free since (tau-1) end-W2 barrier) */  \
    BN[0][0] = *(const bf16x8*)(wbn + 0 * 1024);                                        \
    BN[0][1] = *(const bf16x8*)(wbn + 1 * 1024);                                        \
    BN[1][0] = *(const bf16x8*)(wbn + 2 * 1024);                                        \
    BN[1][1] = *(const bf16x8*)(wbn + 3 * 1024);                                        \
    BN[2][0] = *(const bf16x8*)(wbn + 4 * 1024);                                        \
    BN[2][1] = *(const bf16x8*)(wbn + 5 * 1024);                                        \
    BN[3][0] = *(const bf16x8*)(wbn + 6 * 1024);                                        \
    BN[3][1] = *(const bf16x8*)(wbn + 7 * 1024);                                        \
    stageA((tau) + 1, 0);                                                               \
    stageA((tau) + 1, 1);                                                               \
    /* W0: lo x k0; hide af-lo-k1 */                                                    \
    WLG0();                                                                             \
    __builtin_amdgcn_s_setprio(1);                                                      \
    MMX(0, 0, 0, 0, BC); MMX(0, 1, 0, 0, BC); MMX(0, 2, 0, 0, BC); MMX(0, 3, 0, 0, BC); \
    af[0][1] = *(const bf16x8*)(base + aoffb[0] + un[1]);                               \
    MMX(1, 0, 0, 0, BC); MMX(1, 1, 0, 0, BC); MMX(1, 2, 0, 0, BC); MMX(1, 3, 0, 0, BC); \
    af[1][1] = *(const bf16x8*)(base + aoffb[1] + un[1]);                               \
    MMX(2, 0, 0, 0, BC); MMX(2, 1, 0, 0, BC); MMX(2, 2, 0, 0, BC); MMX(2, 3, 0, 0, BC); \
    af[2][1] = *(const bf16x8*)(base + aoffb[2] + un[1]);                               \
    MMX(3, 0, 0, 0, BC); MMX(3, 1, 0, 0, BC); MMX(3, 2, 0, 0, BC); MMX(3, 3, 0, 0, BC); \
    af[3][1] = *(const bf16x8*)(base + aoffb[3] + un[1]);                               \
    __builtin_amdgcn_s_setprio(0);                                                      \
    /* W1: lo x k1; hide af-hi-k0 */                                                    \
    WLG0();                                                                             \
    __builtin_amdgcn_s_setprio(1);                                                      \
    MMX(0, 0, 1, 0, BC); MMX(0, 1, 1, 0, BC); MMX(0, 2, 1, 0, BC); MMX(0, 3, 1, 0, BC); \
    af[0][0] = *(const bf16x8*)(base + aoffb[4] + un[0]);                               \
    MMX(1, 0, 1, 0, BC); MMX(1, 1, 1, 0, BC); MMX(1, 2, 1, 0, BC); MMX(1, 3, 1, 0, BC); \
    af[1][0] = *(const bf16x8*)(base + aoffb[5] + un[0]);                               \
    MMX(2, 0, 1, 0, BC); MMX(2, 1, 1, 0, BC); MMX(2, 2, 1, 0, BC); MMX(2, 3, 1, 0, BC); \
    af[2][0] = *(const bf16x8*)(base + aoffb[6] + un[0]);                               \
    MMX(3, 0, 1, 0, BC); MMX(3, 1, 1, 0, BC); MMX(3, 2, 1, 0, BC); MMX(3, 3, 1, 0, BC); \
    af[3][0] = *(const bf16x8*)(base + aoffb[7] + un[0]);                               \
    __builtin_amdgcn_s_setprio(0);                                                      \
    /* W2: hi x k0; hide af-hi-k1; drain all (issued ~3 windows ago); ONE barrier */    \
    WLG0();                                                                             \
    __builtin_amdgcn_s_setprio(1);                                                      \
    MMX(0, 0, 0, 4, BC); MMX(0, 1, 0, 4, BC); MMX(0, 2, 0, 4, BC); MMX(0, 3, 0, 4, BC); \
    af[0][1] = *(const bf16x8*)(base + aoffb[4] + un[1]);                               \
    MMX(1, 0, 0, 4, BC); MMX(1, 1, 0, 4, BC); MMX(1, 2, 0, 4, BC); MMX(1, 3, 0, 4, BC); \
    af[1][1] = *(const bf16x8*)(base + aoffb[5] + un[1]);                               \
    MMX(2, 0, 0, 4, BC); MMX(2, 1, 0, 4, BC); MMX(2, 2, 0, 4, BC); MMX(2, 3, 0, 4, BC); \
    af[2][1] = *(const bf16x8*)(base + aoffb[6] + un[1]);                               \
    MMX(3, 0, 0, 4, BC); MMX(3, 1, 0, 4, BC); MMX(3, 2, 0, 4, BC); MMX(3, 3, 0, 4, BC); \
    af[3][1] = *(const bf16x8*)(base + aoffb[7] + un[1]);                               \
    __builtin_amdgcn_s_setprio(0);                                                      \
    asm volatile("s_waitcnt vmcnt(0) lgkmcnt(0)" ::: "memory");                         \
    __builtin_amdgcn_sched_barrier(0);                                                  \
    BAR();                                                                              \
    /* W3: hi x k1; hide NEXT af-lo-k0 */                                               \
    __builtin_amdgcn_s_setprio(1);                                                      \
    MMX(0, 0, 1, 4, BC); MMX(0, 1, 1, 4, BC); MMX(0, 2, 1, 4, BC); MMX(0, 3, 1, 4, BC); \
    af[0][0] = *(const bf16x8*)(nbase + aoffb[0] + un[0]);                              \
    MMX(1, 0, 1, 4, BC); MMX(1, 1, 1, 4, BC); MMX(1, 2, 1, 4, BC); MMX(1, 3, 1, 4, BC); \
    af[1][0] = *(const bf16x8*)(nbase + aoffb[1] + un[0]);                              \
    MMX(2, 0, 1, 4, BC); MMX(2, 1, 1, 4, BC); MMX(2, 2, 1, 4, BC); MMX(2, 3, 1, 4, BC); \
    af[2][0] = *(const bf16x8*)(nbase + aoffb[2] + un[0]);                              \
    MMX(3, 0, 1, 4, BC); MMX(3, 1, 1, 4, BC); MMX(3, 2, 1, 4, BC); MMX(3, 3, 1, 4, BC); \
    af[3][0] = *(const bf16x8*)(nbase + aoffb[3] + un[0]);                              \
    __builtin_amdgcn_s_setprio(0);                                                      \
  }

#pragma unroll 1
  for (int t2 = 0; t2 < 18; ++t2) {          // tiles 0..35
    int tau = t2 * 2;
    TILE_STEADY(tau, bA, bB);
    TILE_STEADY(tau + 1, bB, bA);
  }
  TILE_STEADY(36, bA, bB);                   // stages A(37), loads B(37)->bB

  // ---- last tile 37 (buf1, cur=bB): no staging, no B-next, no barrier ----
  {
    const char* base = smem + 32768;
    WLG0();
    MMX(0, 0, 0, 0, bB); MMX(0, 1, 0, 0, bB); MMX(0, 2, 0, 0, bB); MMX(0, 3, 0, 0, bB);
    af[0][1] = *(const bf16x8*)(base + aoffb[0] + un[1]);
    MMX(1, 0, 0, 0, bB); MMX(1, 1, 0, 0, bB); MMX(1, 2, 0, 0, bB); MMX(1, 3, 0, 0, bB);
    af[1][1] = *(const bf16x8*)(base + aoffb[1] + un[1]);
    MMX(2, 0, 0, 0, bB); MMX(2, 1, 0, 0, bB); MMX(2, 2, 0, 0, bB); MMX(2, 3, 0, 0, bB);
    af[2][1] = *(const bf16x8*)(base + aoffb[2] + un[1]);
    MMX(3, 0, 0, 0, bB); MMX(3, 1, 0, 0, bB); MMX(3, 2, 0, 0, bB); MMX(3, 3, 0, 0, bB);
    af[3][1] = *(const bf16x8*)(base + aoffb[3] + un[1]);
    WLG0();
    MMX(0, 0, 1, 0, bB); MMX(0, 1, 1, 0, bB); MMX(0, 2, 1, 0, bB); MMX(0, 3, 1, 0, bB);
    af[0][0] = *(const bf16x8*)(base + aoffb[4] + un[0]);
    MMX(1, 0, 1, 0, bB); MMX(1, 1, 1, 0, bB); MMX(1, 2, 1, 0, bB); MMX(1, 3, 1, 0, bB);
    af[1][0] = *(const bf16x8*)(base + aoffb[5] + un[0]);
    MMX(2, 0, 1, 0, bB); MMX(2, 1, 1, 0, bB); MMX(2, 2, 1, 0, bB); MMX(2, 3, 1, 0, bB);
    af[2][0] = *(const bf16x8*)(base + aoffb[6] + un[0]);
    MMX(3, 0, 1, 0, bB); MMX(3, 1, 1, 0, bB); MMX(3, 2, 1, 0, bB); MMX(3, 3, 1, 0, bB);
    af[3][0] = *(const bf16x8*)(base + aoffb[7] + un[0]);
    WLG0();
    MMX(0, 0, 0, 4, bB); MMX(0, 1, 0, 4, bB); MMX(0, 2, 0, 4, bB); MMX(0, 3, 0, 4, bB);
    af[0][1] = *(const bf16x8*)(base + aoffb[4] + un[1]);
    MMX(1, 0, 0, 4, bB); MMX(1, 1, 0, 4, bB); MMX(1, 2, 0, 4, bB); MMX(1, 3, 0, 4, bB);
    af[1][1] = *(const bf16x8*)(base + aoffb[5] + un[1]);
    MMX(2, 0, 0, 4, bB); MMX(2, 1, 0, 4, bB); MMX(2, 2, 0, 4, bB); MMX(2, 3, 0, 4, bB);
    af[2][1] = *(const bf16x8*)(base + aoffb[6] + un[1]);
    MMX(3, 0, 0, 4, bB); MMX(3, 1, 0, 4, bB); MMX(3, 2, 0, 4, bB); MMX(3, 3, 0, 4, bB);
    af[3][1] = *(const bf16x8*)(base + aoffb[7] + un[1]);
    WLG0();
    MMX(0, 0, 1, 4, bB); MMX(0, 1, 1, 4, bB); MMX(0, 2, 1, 4, bB); MMX(0, 3, 1, 4, bB);
    MMX(1, 0, 1, 4, bB); MMX(1, 1, 1, 4, bB); MMX(1, 2, 1, 4, bB); MMX(1, 3, 1, 4, bB);
    MMX(2, 0, 1, 4, bB); MMX(2, 1, 1, 4, bB); MMX(2, 2, 1, 4, bB); MMX(2, 3, 1, 4, bB);
    MMX(3, 0, 1, 4, bB); MMX(3, 1, 1, 4, bB); MMX(3, 2, 1, 4, bB); MMX(3, 3, 1, 4, bB);
  }
#undef MMX
#undef TILE_STEADY

  __syncthreads();  // all waves done before epilogue overwrites smem

  // ---- epilogue 1: raw conv -> cv via 64KB LDS repack, two 128-row passes ----
  unsigned short* l16 = (unsigned short*)smem;
#pragma unroll
  for (int p = 0; p < 2; ++p) {
    if (wm == p) {
#pragma unroll
      for (int mf = 0; mf < 8; ++mf)
#pragma unroll
        for (int nf = 0; nf < 4; ++nf)
#pragma unroll
          for (int r = 0; r < 4; ++r) {
            int rowl = mf * 16 + (lane >> 4) * 4 + r;           // local row 0..127
            int col = wn * 64 + nf * 16 + (lane & 15);
            int colx = col ^ (((rowl >> 2) & 3) << 3);          // bit7 (p*128) doesn't affect bits[3:2]
            l16[rowl * 256 + colx] = f2b(acc[mf][nf][r]);
          }
    }
    __syncthreads();
#pragma unroll
    for (int i = 0; i < 8; ++i) {
      int q = tid + 512 * i;                 // 4096 chunks of 16B
      int prow = q >> 5, c16 = q & 31;
      int c16g = c16 ^ ((prow >> 2) & 3);
      *(u16x8*)(cv + ((size_t)(pix0 + p * 128 + prow) * 512 + n0 + c16g * 8)) =
          *(const u16x8*)(l16 + q * 8);
    }
    __syncthreads();
  }

  // ---- epilogue 2: BN partial stats from f32 acc ----
  float* lf = (float*)smem;
  float sv[4], qv[4];
#pragma unroll
  for (int nf = 0; nf < 4; ++nf) {
    float s = 0.f, q = 0.f;
#pragma unroll
    for (int mf = 0; mf < 8; ++mf)
#pragma unroll
      for (int r = 0; r < 4; ++r) { float v = acc[mf][nf][r]; s += v; q += v * v; }
    s += __shfl_xor(s, 16); s += __shfl_xor(s, 32);
    q += __shfl_xor(q, 16); q += __shfl_xor(q, 32);
    sv[nf] = s; qv[nf] = q;
  }
  if (lane < 16) {
#pragma unroll
    for (int nf = 0; nf < 4; ++nf) {
      int ch = wn * 64 + nf * 16 + lane;
      lf[wm * 256 + ch] = sv[nf];
      lf[512 + wm * 256 + ch] = qv[nf];
    }
  }
  __syncthreads();
  if (tid < 256) {
    float S = lf[tid] + lf[256 + tid];
    float Q = lf[512 + tid] + lf[768 + tid];
    ((float2*)ps)[(size_t)(n0 + tid) * 256 + mt] = make_float2(S, Q);
  }
}

// ---------------- BN finalize: scale/bias (16 blocks, shfl-reduced) ----------------
__global__ void k_bnfinal(const float* __restrict__ ps, const float* __restrict__ gamma,
                          const float* __restrict__ beta, float* __restrict__ sb) {
  int c = blockIdx.x * 32 + (threadIdx.x >> 3);
  int sl = threadIdx.x & 7;
  const float2* p2 = (const float2*)ps + (size_t)c * 256 + sl * 32;
  float s = 0.f, q = 0.f;
#pragma unroll 8
  for (int i = 0; i < 32; ++i) { float2 v = p2[i]; s += v.x; q += v.y; }
  s += __shfl_xor(s, 1); s += __shfl_xor(s, 2); s += __shfl_xor(s, 4);
  q += __shfl_xor(q, 1); q += __shfl_xor(q, 2); q += __shfl_xor(q, 4);
  if (sl == 0) {
    float mean = s * (1.0f / 65536.0f);
    float var = q * (1.0f / 65536.0f) - mean * mean;
    float sc = gamma[c] / sqrtf(var + 1e-5f);
    sb[c] = sc;
    sb[512 + c] = beta[c] - mean * sc;
  }
}

// ---------------- head: BN+leaky fused A-load, 256px x 64out GEMM (K=512) + decode ----------------
__global__ __launch_bounds__(256) void k_head(const unsigned short* __restrict__ cv,
                                              const unsigned short* __restrict__ w2,
                                              const float* __restrict__ bl,
                                              const float* __restrict__ bm,
                                              const float* __restrict__ sb,
                                              float* __restrict__ out) {
  __shared__ float lo[256][59];
  __shared__ float sS[512], sBb[512];
  int tid = threadIdx.x, lane = tid & 63, wv = tid >> 6;
  int pix0 = blockIdx.x * 256;
  sS[tid] = sb[tid]; sS[256 + tid] = sb[256 + tid];
  sBb[tid] = sb[512 + tid]; sBb[256 + tid] = sb[768 + tid];
  __syncthreads();

  f32x4 acc[4][4];
#pragma unroll
  for (int mf = 0; mf < 4; ++mf)
#pragma unroll
    for (int nf = 0; nf < 4; ++nf) acc[mf][nf] = (f32x4){0.f, 0.f, 0.f, 0.f};
  int ko = lane >> 4;

  for (int k0 = 0; k0 < 512; k0 += 32) {
    int c0 = k0 + ko * 8;
    f32x4 sc0 = *(const f32x4*)&sS[c0], sc1 = *(const f32x4*)&sS[c0 + 4];
    f32x4 bo0 = *(const f32x4*)&sBb[c0], bo1 = *(const f32x4*)&sBb[c0 + 4];
    bf16x8 a[4], bg[4];
#pragma unroll
    for (int f = 0; f < 4; ++f) {
      bg[f] = *(const bf16x8*)(w2 + (size_t)(f * 16 + (lane & 15)) * 512 + c0);
      u16x8 raw = *(const u16x8*)(cv + (size_t)(pix0 + wv * 64 + f * 16 + (lane & 15)) * 512 + c0);
      u16x8 av;
#pragma unroll
      for (int jj = 0; jj < 4; ++jj) {
        float v = b2f(raw[jj]) * sc0[jj] + bo0[jj];
        v = (v > 0.f) ? v : 0.1f * v;
        av[jj] = f2b(v);
      }
#pragma unroll
      for (int jj = 0; jj < 4; ++jj) {
        float v = b2f(raw[4 + jj]) * sc1[jj] + bo1[jj];
        v = (v > 0.f) ? v : 0.1f * v;
        av[4 + jj] = f2b(v);
      }
      a[f] = __builtin_bit_cast(bf16x8, av);
    }
#pragma unroll
    for (int mf = 0; mf < 4; ++mf)
#pragma unroll
      for (int nf = 0; nf < 4; ++nf)
        acc[mf][nf] = __builtin_amdgcn_mfma_f32_16x16x32_bf16(a[mf], bg[nf], acc[mf][nf], 0, 0, 0);
  }

  float bias[4]; int colv[4];
#pragma unroll
  for (int nf = 0; nf < 4; ++nf) {
    int col = nf * 16 + (lane & 15);
    colv[nf] = col;
    bias[nf] = (col < 10) ? bl[col] : ((col < 58) ? bm[col - 10] : 0.f);
  }
#pragma unroll
  for (int mf = 0; mf < 4; ++mf)
#pragma unroll
    for (int nf = 0; nf < 4; ++nf)
#pragma unroll
      for (int r = 0; r < 4; ++r) {
        int row = wv * 64 + mf * 16 + (lane >> 4) * 4 + r;
        if (colv[nf] < 58) lo[row][colv[nf]] = acc[mf][nf][r] + bias[nf];
      }
  __syncthreads();

  // ---- decode: one thread = one pixel ----
  int pix = pix0 + tid;
  int b = pix >> 12, pi = pix & 4095;
  int yi = pi >> 6, xi = pi & 63;
  float X = (float)xi, Y = (float)yi;
  const float* O = lo[tid];

  float* outP = out;
  float* outB = out + 655360;
  float* outOL = out + 1572864;
  float* outOC = out + 2752512;
  float* outML = out + 3932160;
  float* outMC = out + 4521984;
  float* outWC = out + 5111808;
  float* outOD = out + 5636096;

  float pr[10];
#pragma unroll
  for (int i = 0; i < 10; ++i) { pr[i] = O[i]; outP[(size_t)pix * 10 + i] = pr[i]; }
  const float st = 8.f, ist = 0.125f;
  float l0 = pr[0] * pr[0] * st, l1 = pr[1] * pr[1] * st;
  float l2 = pr[2] * pr[2] * st, l3 = pr[3] * pr[3] * st;
  float cx = X * st + 4.f, cy = Y * st + 4.f;
  float xmin = cx - l3, ymin = cy - l0, xmax = cx + l1, ymax = cy + l2;
  float w = l1 + l3, h = l0 + l2;
  float xc = 0.5f * (xmax + xmin), yc = 0.5f * (ymax + ymin);
  float r = sigf(pr[8]);
  float maskr = (r > 0.9f) ? 0.f : 1.f;
  float s0 = sigf(pr[4]) * maskr, s1 = sigf(pr[5]) * maskr;
  float s2 = sigf(pr[6]) * maskr, s3 = sigf(pr[7]) * maskr;
  float conf = sigf(pr[9]);
  {
    size_t bo = (size_t)pix * 14;
    outB[bo + 0] = xc; outB[bo + 1] = yc; outB[bo + 2] = w; outB[bo + 3] = h;
    outB[bo + 4] = s0; outB[bo + 5] = s1; outB[bo + 6] = s2; outB[bo + 7] = s3;
    outB[bo + 8] = r;  outB[bo + 9] = l0; outB[bo + 10] = l1; outB[bo + 11] = l2;
    outB[bo + 12] = l3; outB[bo + 13] = conf;
  }
  float x1 = xmin + s0 * w, x7 = xmax - s2 * w;
  float y5 = ymin + s1 * h, y3 = ymax - s3 * h;
  float xob = 0.5f * (x1 + x7), yob = 0.5f * (y5 + y3);
  float ov[22];
#pragma unroll
  for (int jj = 0; jj < 22; ++jj) ov[jj] = sigf(O[28 + jj]);
  float eps = ceilf(0.01f * w);
  bool c0 = x1 < xmin + eps;
  float xp0 = c0 ? x1 : xmin + ov[0] * (x1 - xmin);
  float yp0 = c0 ? ymin + ov[0] * (y3 - ymin)
                 : (y3 - ymin) / (xmin - x1 + 1e-8f) * (xp0 - x1) + ymin;
  bool c2 = x1 > xmax - eps;
  float xp2 = c2 ? x1 : xmax - ov[1] * (xmax - x1);
  float yp2 = c2 ? ymin + ov[1] * (y5 - ymin)
                 : (y5 - ymin) / (xmax - x1 + 1e-8f) * (xp2 - x1) + ymin;
  bool c6 = x7 < xmin + eps;
  float xp6 = c6 ? x7 : xmin + ov[2] * (x7 - xmin);
  float yp6 = c6 ? ymax - ov[2] * (ymax - y3)
                 : (y3 - ymax) / (xmin - x7 + 1e-8f) * (xp6 - x7) + ymax;
  bool c8c = x7 > xmax - eps;
  float xp8 = c8c ? x7 : xmax - ov[3] * (xmax - x7);
  float yp8 = c8c ? ymax - ov[3] * (ymax - y5)
                  : (y5 - ymax) / (xmax - x7 + 1e-8f) * (xp8 - x7) + ymax;

  size_t olb = ((size_t)b * 18) * 4096 + pi;
  outOL[olb + 0 * 4096] = yp0 * ist + 1.f - Y;
  outOL[olb + 1 * 4096] = xp0 * ist + 1.f - X;
  outOL[olb + 2 * 4096] = ymin * ist + 1.f - Y;
  outOL[olb + 3 * 4096] = x1 * ist - X;
  outOL[olb + 4 * 4096] = yp2 * ist + 1.f - Y;
  outOL[olb + 5 * 4096] = xp2 * ist - 1.f - X;
  outOL[olb + 6 * 4096] = y3 * ist - Y;
  outOL[olb + 7 * 4096] = xmin * ist + 1.f - X;
  outOL[olb + 8 * 4096] = 0.f;
  outOL[olb + 9 * 4096] = 0.f;
  outOL[olb + 10 * 4096] = y5 * ist - Y;
  outOL[olb + 11 * 4096] = xmax * ist - 1.f - X;
  outOL[olb + 12 * 4096] = yp6 * ist - 1.f - Y;
  outOL[olb + 13 * 4096] = xp6 * ist + 1.f - X;
  outOL[olb + 14 * 4096] = ymax * ist - 1.f - Y;
  outOL[olb + 15 * 4096] = x7 * ist - X;
  outOL[olb + 16 * 4096] = yp8 * ist - 1.f - Y;
  outOL[olb + 17 * 4096] = xp8 * ist - 1.f - X;

  float A1 = x1 - xmax, B1 = ymin - y5, A2 = xmin - x7, B2 = y3 - ymax;
  float width = 0.5f * (sqrtf(A1 * A1 + B1 * B1) + sqrtf(A2 * A2 + B2 * B2));
  float C1 = xmin - x1, D1 = y3 - ymin, C2 = x7 - xmax, D2 = ymax - y5;
  float height = 0.5f * (sqrtf(C1 * C1 + D1 * D1) + sqrtf(C2 * C2 + D2 * D2));
  float ang = 0.5f * (atanf((y5 - ymin) / (xmax - x1 + 1e-4f)) +
                      atanf((ymax - y3) / (x7 - xmin + 1e-4f)));
  float ca = cosf(ang), sa = sinf(ang);
  const float DD = 0.70710678118654752f;
  const float dyc[9] = {DD, 1.f, DD, 0.f, 0.f, 0.f, -DD, -1.f, -DD};
  const float dxc[9] = {DD, 0.f, -DD, 1.f, 0.f, -1.f, DD, 0.f, -DD};
  size_t ocb = ((size_t)b * 18) * 4096 + pi;
  size_t odb = (size_t)pix * 18;
#pragma unroll
  for (int k = 0; k < 9; ++k) {
    float xd = xob - 0.5f * width + ov[13 + k] * width;
    float yd = yob - 0.5f * height + ov[4 + k] * height;
    float ddx = xd - xob, ddy = yd - yob;
    float xd0 = ca * ddx - sa * ddy + xob;
    float xdc = fminf(fmaxf(xd0, xmin), xmax);
    float yd0 = sa * ddx + ca * ddy + yob;
    float ydc = fminf(fmaxf(yd0, ymin), ymax);
    outOC[ocb + (size_t)(2 * k) * 4096] = ydc * ist + dyc[k] - Y;
    outOC[ocb + (size_t)(2 * k + 1) * 4096] = xdc * ist + dxc[k] - X;
    outOD[odb + k] = xdc;
    outOD[odb + 9 + k] = ydc;
  }
  size_t mlb = ((size_t)b * 9) * 4096 + pi;
#pragma unroll
  for (int k = 0; k < 9; ++k) outML[mlb + (size_t)k * 4096] = sigf(O[10 + k]);
#pragma unroll
  for (int k = 0; k < 9; ++k) outMC[mlb + (size_t)k * 4096] = sigf(O[19 + k]);
  float v8[8], mx = -1e30f;
#pragma unroll
  for (int k = 0; k < 8; ++k) { v8[k] = O[50 + k]; mx = fmaxf(mx, v8[k]); }
  float sm = 0.f;
#pragma unroll
  for (int k = 0; k < 8; ++k) { v8[k] = __expf(v8[k] - mx); sm += v8[k]; }
  float inv = 1.f / sm;
  size_t wcb = ((size_t)b * 8) * 4096 + pi;
#pragma unroll
  for (int k = 0; k < 8; ++k) outWC[wcb + (size_t)k * 4096] = v8[k] * inv;
}

// ---------------- launch ----------------
extern "C" void kernel_launch(void* const* d_in, const int* in_sizes, int n_in,
                              void* d_out, int out_size, void* d_ws, size_t ws_size,
                              hipStream_t stream) {
  const float* in1 = (const float*)d_in[0];
  const float* wconv = (const float*)d_in[1];
  const float* gamma = (const float*)d_in[2];
  const float* beta = (const float*)d_in[3];
  const float* wloc = (const float*)d_in[4];
  const float* bloc = (const float*)d_in[5];
  const float* wmask = (const float*)d_in[6];
  const float* bmask = (const float*)d_in[7];
  unsigned char* ws = (unsigned char*)d_ws;
  unsigned short* xp = (unsigned short*)(ws + XP_OFF);
  unsigned short* wt2 = (unsigned short*)(ws + WT_OFF);
  unsigned short* w2 = (unsigned short*)(ws + W2_OFF);
  unsigned short* cv = (unsigned short*)(ws + CV_OFF);
  float* ps = (float*)(ws + PS_OFF);
  float* sb = (float*)(ws + SB_OFF);
  float* out = (float*)d_out;

  (void)hipFuncSetAttribute(reinterpret_cast<const void*>(k_conv8),
                            hipFuncAttributeMaxDynamicSharedMemorySize, 65536);

  k_prep<<<dim3(5785), dim3(256), 0, stream>>>(wconv, wloc, wmask, xp, wt2, w2);
  k_pack_in<<<dim3(8192), dim3(256), 0, stream>>>(in1, xp);
  k_conv8<<<dim3(512), dim3(512), 65536, stream>>>(xp, wt2, cv, ps);
  k_bnfinal<<<dim3(16), dim3(256), 0, stream>>>(ps, gamma, beta, sb);
  k_head<<<dim3(256), dim3(256), 0, stream>>>(cv, w2, bloc, bmask, sb, out);
}

// Round 9
// 203.481 us; speedup vs baseline: 1.0863x; 1.0863x over previous
//
#include <hip/hip_runtime.h>

typedef __attribute__((ext_vector_type(4))) float f32x4;
typedef __attribute__((ext_vector_type(4))) unsigned int u32x4;
typedef __attribute__((ext_vector_type(8))) unsigned short u16x8;
typedef __attribute__((ext_vector_type(8))) __bf16 bf16x8;

#define DEVFN static __device__ __forceinline__

DEVFN unsigned short f2b(float f) {
  unsigned u = __builtin_bit_cast(unsigned, f);
  u += 0x7fffu + ((u >> 16) & 1u);
  return (unsigned short)(u >> 16);
}
DEVFN float b2f(unsigned short h) {
  unsigned u = ((unsigned)h) << 16;
  return __builtin_bit_cast(float, u);
}
DEVFN float sigf(float x) { return 1.0f / (1.0f + __expf(-x)); }

// ---------------- geometry ----------------
#define CS 264
#define KPAD 2432
#define NTILE 38

// ---------------- workspace layout (bytes) ----------------
#define XP_BYTES (16ull*66*66*CS*2)
#define WT_BYTES (512ull*KPAD*2)       // wt2: fragment-linear packed B
#define W2_BYTES (64ull*512*2)
#define CV_BYTES (65536ull*512*2)
#define PS_BYTES (512ull*256*2*4)
#define XP_OFF 0ull
#define WT_OFF (XP_OFF + XP_BYTES)
#define W2_OFF (WT_OFF + WT_BYTES)
#define CV_OFF (W2_OFF + W2_BYTES)
#define PS_OFF (CV_OFF + CV_BYTES)
#define SB_OFF (PS_OFF + PS_BYTES)

#define GLOAD16(gp, lp) __builtin_amdgcn_global_load_lds( \
    (__attribute__((address_space(1))) void*)(gp),        \
    (__attribute__((address_space(3))) void*)(lp), 16, 0, 0)

#define BAR()  do { __builtin_amdgcn_s_barrier(); __builtin_amdgcn_sched_barrier(0); } while (0)
#define WLG0() do { asm volatile("s_waitcnt lgkmcnt(0)" ::: "memory"); __builtin_amdgcn_sched_barrier(0); } while (0)

// ---------------- merged prep kernel (pack_in + border + grid + wt2 + w2 in ONE launch) ----------------
// [0,8192) pack_in | [8192,8729) zero-border | [8729,8985) grid ch | [8985,13849) conv B | [13849,13977) head w
__global__ void k_prep(const float* __restrict__ in1, const float* __restrict__ wc,
                       const float* __restrict__ wl, const float* __restrict__ wm,
                       unsigned short* __restrict__ xp, unsigned short* __restrict__ wt2,
                       unsigned short* __restrict__ w2) {
  __shared__ float lt[32][65];
  int bid = blockIdx.x, tid = threadIdx.x;
  if (bid < 8192) {                        // pack_in: interior cells, ch<256
    int cg = bid & 7, y = (bid >> 3) & 63, b = bid >> 9;
    int x = tid & 63, cr = tid >> 6;
#pragma unroll
    for (int i = 0; i < 8; ++i) {
      int cl = i * 4 + cr;
      lt[cl][x] = in1[(((size_t)(b * 256 + cg * 32 + cl) * 64 + y) * 64) + x];
    }
    __syncthreads();
    int xx = tid >> 2, ch = tid & 3;
    u16x8 v;
#pragma unroll
    for (int j = 0; j < 8; ++j) v[j] = f2b(lt[ch * 8 + j][xx]);
    size_t base = ((size_t)((b * 66 + y + 1) * 66 + xx + 1)) * CS + cg * 32 + ch * 8;
    *(u16x8*)(xp + base) = v;
  } else if (bid < 8729) {                 // border cells, all ch
    int idx = (bid - 8192) * 256 + tid;
    if (idx >= 137280) return;
    int cell_i = idx / 33, u = idx - cell_i * 33;
    int b = cell_i / 260, r = cell_i - b * 260;
    int y, x;
    if (r < 66) { y = 0; x = r; }
    else if (r < 132) { y = 65; x = r - 66; }
    else if (r < 196) { y = r - 131; x = 0; }
    else { y = r - 195; x = 65; }
    int cell = (b * 66 + y) * 66 + x;
    *(u32x4*)((unsigned char*)xp + (size_t)cell * (CS * 2) + u * 16) = (u32x4){0u, 0u, 0u, 0u};
  } else if (bid < 8985) {                 // grid channels 256,257 + pad
    int pid = (bid - 8729) * 256 + tid;
    int b = pid >> 12, pi = pid & 4095, y = pi >> 6, x = pi & 63;
    u16x8 v0 = (u16x8){0, 0, 0, 0, 0, 0, 0, 0};
    v0[0] = f2b((float)x); v0[1] = f2b((float)y);
    *(u16x8*)(xp + ((size_t)((b * 66 + y + 1) * 66 + x + 1)) * CS + 256) = v0;
  } else if (bid < 13849) {                // conv B fragment-linear: 512*2432
    int idx = (bid - 8985) * 256 + tid;
    int o = idx / KPAD, k = idx - o * KPAD;
    int dy = k / 800, t = k - dy * 800;
    int dx = t / CS, ci = t - dx * CS;
    float v = (dy < 3 && dx < 3 && ci < 258) ? wc[(size_t)(o * 258 + ci) * 9 + dy * 3 + dx] : 0.f;
    int ntv = o >> 8, o2 = o & 255, wn = o2 >> 6, o3 = o2 & 63, nf = o3 >> 4, r = o3 & 15;
    int tau = k >> 6, k2 = k & 63, kk = k2 >> 5, k3 = k2 & 31, ko = k3 >> 3, e = k3 & 7;
    size_t off = ((size_t)(((ntv * 38 + tau) * 4 + wn) * 8 + nf * 2 + kk)) * 512 + (ko * 16 + r) * 8 + e;
    wt2[off] = f2b(v);
  } else {                                 // head weights
    int idx = (bid - 13849) * 256 + tid;
    int o = idx >> 9, k = idx & 511;
    float v = 0.f;
    if (o < 10) v = wl[o * 512 + k];
    else if (o < 58) v = wm[(o - 10) * 512 + k];
    w2[idx] = f2b(v);
  }
}

// ---------------- conv: 256x256 tile, BK=64; A via 64KB LDS dbuf, B via coalesced global->reg ----------------
// Counted-wait schedule: tile top issues 4 stageA(tau+1) gload_lds; W2-end issues 8 B(tau+1) reg loads
// then s_waitcnt vmcnt(8) lgkmcnt(0) (drains ONLY the A-stages; B stays in flight across the single
// barrier, consumed 1 window later with compiler's counted wait). Never vmcnt(0) in steady state.
__global__ __launch_bounds__(512, 2) void k_conv8(const unsigned short* __restrict__ xp,
                                                  const unsigned short* __restrict__ wt2,
                                                  unsigned short* __restrict__ cv,
                                                  float* __restrict__ ps) {
  extern __shared__ char smem[];
  int tid = threadIdx.x, lane = tid & 63, wv = tid >> 6;
  int wm = wv >> 2, wn = wv & 3;
  int bid = blockIdx.x;
  int xcd = bid & 7, j = bid >> 3;
  int nt = j & 1;
  int mt = xcd * 32 + (j >> 1);
  int n0 = nt * 256;
  int pix0 = mt * 256;
  int b = pix0 >> 12, pi0 = pix0 & 4095;

  // ---- A staging constants ----
  int srow = tid >> 3;
  int ug = (tid & 7) ^ (srow & 7);
  unsigned cellB[4];
#pragma unroll
  for (int jj = 0; jj < 4; ++jj) {
    int pi = pi0 + srow + 64 * jj;
    int yy = pi >> 6, xx = pi & 63;
    cellB[jj] = (unsigned)((b * 66 + yy) * 66 + xx) * (CS * 2);
  }

  auto stageA = [&](int tau, int h) {
    int buf = tau & 1;
    unsigned k = (unsigned)tau * 64u + (unsigned)ug * 8u;
    unsigned dy = k / 800u;
    unsigned t = k - dy * 800u;
    unsigned off = dy * (66u * CS * 2u) + t * 2u;
    const unsigned char* g = (const unsigned char*)xp;
    char* l = smem + buf * 32768 + h * 16384;
    GLOAD16(g + cellB[h * 2] + off, l + tid * 16);
    GLOAD16(g + cellB[h * 2 + 1] + off, l + 8192 + tid * 16);
  };

  // ---- fragment read constants ----
  unsigned aoffb[8];
#pragma unroll
  for (int mf = 0; mf < 8; ++mf) aoffb[mf] = (unsigned)(wm * 128 + mf * 16 + (lane & 15)) * 128u;
  int ko = (lane >> 4) & 3, xm = lane & 7;
  unsigned un[2];
#pragma unroll
  for (int kk = 0; kk < 2; ++kk) un[kk] = (unsigned)(((kk * 4 + ko) ^ xm) * 16);

  // B base for this wave: chunks of 1KB, index ((nt*38+tau)*4+wn)*8 + nf*2+kk
  const char* wb = (const char*)wt2 + ((size_t)(nt * 38 * 4 + wn) * 8) * 1024 + (size_t)lane * 16;
  const size_t WTAU = 4 * 8 * 1024;   // byte stride per tau

  f32x4 acc[8][4];
#pragma unroll
  for (int i = 0; i < 8; ++i)
#pragma unroll
    for (int jj = 0; jj < 4; ++jj) acc[i][jj] = (f32x4){0.f, 0.f, 0.f, 0.f};

  bf16x8 af[4][2], bA[4][2], bB[4][2];

  // ---- prologue: stage A(0) (4 loads), then B(0)->bA (8 loads); vmcnt(8) drains only A(0) ----
  stageA(0, 0); stageA(0, 1);
#pragma unroll
  for (int nf = 0; nf < 4; ++nf) {
    bA[nf][0] = *(const bf16x8*)(wb + (nf * 2 + 0) * 1024);
    bA[nf][1] = *(const bf16x8*)(wb + (nf * 2 + 1) * 1024);
  }
  asm volatile("s_waitcnt vmcnt(8)" ::: "memory");
  __builtin_amdgcn_sched_barrier(0);
  BAR();
  {
    const char* base0 = smem;
#pragma unroll
    for (int s = 0; s < 4; ++s) af[s][0] = *(const bf16x8*)(base0 + aoffb[s] + un[0]);
  }

#define MMX(mi, ni, kk, ab, BC) acc[(ab) + (mi)][(ni)] = \
    __builtin_amdgcn_mfma_f32_16x16x32_bf16(af[(mi)][(kk)], BC[(ni)][(kk)], acc[(ab) + (mi)][(ni)], 0, 0, 0)

// steady tile: top issues stageA(tau+1); W2-end issues B(tau+1)->BN then vmcnt(8); ONE barrier
#define TILE_STEADY(tau, BC, BN)                                                        \
  {                                                                                     \
    const char* base = smem + ((tau) & 1) * 32768;                                      \
    const char* nbase = smem + (((tau) + 1) & 1) * 32768;                               \
    const char* wbn = wb + (size_t)((tau) + 1) * WTAU;                                  \
    /* top: A-stages only (max slack to the W2-end counted wait) */                     \
    stageA((tau) + 1, 0);                                                               \
    stageA((tau) + 1, 1);                                                               \
    /* W0: lo x k0; hide af-lo-k1 (compiler waits BC regs with counted vmcnt) */        \
    WLG0();                                                                             \
    __builtin_amdgcn_s_setprio(1);                                                      \
    MMX(0, 0, 0, 0, BC); MMX(0, 1, 0, 0, BC); MMX(0, 2, 0, 0, BC); MMX(0, 3, 0, 0, BC); \
    af[0][1] = *(const bf16x8*)(base + aoffb[0] + un[1]);                               \
    MMX(1, 0, 0, 0, BC); MMX(1, 1, 0, 0, BC); MMX(1, 2, 0, 0, BC); MMX(1, 3, 0, 0, BC); \
    af[1][1] = *(const bf16x8*)(base + aoffb[1] + un[1]);                               \
    MMX(2, 0, 0, 0, BC); MMX(2, 1, 0, 0, BC); MMX(2, 2, 0, 0, BC); MMX(2, 3, 0, 0, BC); \
    af[2][1] = *(const bf16x8*)(base + aoffb[2] + un[1]);                               \
    MMX(3, 0, 0, 0, BC); MMX(3, 1, 0, 0, BC); MMX(3, 2, 0, 0, BC); MMX(3, 3, 0, 0, BC); \
    af[3][1] = *(const bf16x8*)(base + aoffb[3] + un[1]);                               \
    __builtin_amdgcn_s_setprio(0);                                                      \
    /* W1: lo x k1; hide af-hi-k0 */                                                    \
    WLG0();                                                                             \
    __builtin_amdgcn_s_setprio(1);                                                      \
    MMX(0, 0, 1, 0, BC); MMX(0, 1, 1, 0, BC); MMX(0, 2, 1, 0, BC); MMX(0, 3, 1, 0, BC); \
    af[0][0] = *(const bf16x8*)(base + aoffb[4] + un[0]);                               \
    MMX(1, 0, 1, 0, BC); MMX(1, 1, 1, 0, BC); MMX(1, 2, 1, 0, BC); MMX(1, 3, 1, 0, BC); \
    af[1][0] = *(const bf16x8*)(base + aoffb[5] + un[0]);                               \
    MMX(2, 0, 1, 0, BC); MMX(2, 1, 1, 0, BC); MMX(2, 2, 1, 0, BC); MMX(2, 3, 1, 0, BC); \
    af[2][0] = *(const bf16x8*)(base + aoffb[6] + un[0]);                               \
    MMX(3, 0, 1, 0, BC); MMX(3, 1, 1, 0, BC); MMX(3, 2, 1, 0, BC); MMX(3, 3, 1, 0, BC); \
    af[3][0] = *(const bf16x8*)(base + aoffb[7] + un[0]);                               \
    __builtin_amdgcn_s_setprio(0);                                                      \
    /* W2: hi x k0; hide af-hi-k1; issue B(tau+1); counted vmcnt(8); ONE barrier */     \
    WLG0();                                                                             \
    __builtin_amdgcn_s_setprio(1);                                                      \
    MMX(0, 0, 0, 4, BC); MMX(0, 1, 0, 4, BC); MMX(0, 2, 0, 4, BC); MMX(0, 3, 0, 4, BC); \
    af[0][1] = *(const bf16x8*)(base + aoffb[4] + un[1]);                               \
    MMX(1, 0, 0, 4, BC); MMX(1, 1, 0, 4, BC); MMX(1, 2, 0, 4, BC); MMX(1, 3, 0, 4, BC); \
    af[1][1] = *(const bf16x8*)(base + aoffb[5] + un[1]);                               \
    MMX(2, 0, 0, 4, BC); MMX(2, 1, 0, 4, BC); MMX(2, 2, 0, 4, BC); MMX(2, 3, 0, 4, BC); \
    af[2][1] = *(const bf16x8*)(base + aoffb[6] + un[1]);                               \
    MMX(3, 0, 0, 4, BC); MMX(3, 1, 0, 4, BC); MMX(3, 2, 0, 4, BC); MMX(3, 3, 0, 4, BC); \
    af[3][1] = *(const bf16x8*)(base + aoffb[7] + un[1]);                               \
    __builtin_amdgcn_s_setprio(0);                                                      \
    BN[0][0] = *(const bf16x8*)(wbn + 0 * 1024);                                        \
    BN[0][1] = *(const bf16x8*)(wbn + 1 * 1024);                                        \
    BN[1][0] = *(const bf16x8*)(wbn + 2 * 1024);                                        \
    BN[1][1] = *(const bf16x8*)(wbn + 3 * 1024);                                        \
    BN[2][0] = *(const bf16x8*)(wbn + 4 * 1024);                                        \
    BN[2][1] = *(const bf16x8*)(wbn + 5 * 1024);                                        \
    BN[3][0] = *(const bf16x8*)(wbn + 6 * 1024);                                        \
    BN[3][1] = *(const bf16x8*)(wbn + 7 * 1024);                                        \
    asm volatile("s_waitcnt vmcnt(8) lgkmcnt(0)" ::: "memory");                         \
    __builtin_amdgcn_sched_barrier(0);                                                  \
    BAR();                                                                              \
    /* W3: hi x k1; hide NEXT af-lo-k0 */                                               \
    __builtin_amdgcn_s_setprio(1);                                                      \
    MMX(0, 0, 1, 4, BC); MMX(0, 1, 1, 4, BC); MMX(0, 2, 1, 4, BC); MMX(0, 3, 1, 4, BC); \
    af[0][0] = *(const bf16x8*)(nbase + aoffb[0] + un[0]);                              \
    MMX(1, 0, 1, 4, BC); MMX(1, 1, 1, 4, BC); MMX(1, 2, 1, 4, BC); MMX(1, 3, 1, 4, BC); \
    af[1][0] = *(const bf16x8*)(nbase + aoffb[1] + un[0]);                              \
    MMX(2, 0, 1, 4, BC); MMX(2, 1, 1, 4, BC); MMX(2, 2, 1, 4, BC); MMX(2, 3, 1, 4, BC); \
    af[2][0] = *(const bf16x8*)(nbase + aoffb[2] + un[0]);                              \
    MMX(3, 0, 1, 4, BC); MMX(3, 1, 1, 4, BC); MMX(3, 2, 1, 4, BC); MMX(3, 3, 1, 4, BC); \
    af[3][0] = *(const bf16x8*)(nbase + aoffb[3] + un[0]);                              \
    __builtin_amdgcn_s_setprio(0);                                                      \
  }

#pragma unroll 1
  for (int t2 = 0; t2 < 18; ++t2) {          // tiles 0..35
    int tau = t2 * 2;
    TILE_STEADY(tau, bA, bB);
    TILE_STEADY(tau + 1, bB, bA);
  }
  TILE_STEADY(36, bA, bB);                   // stages A(37), loads B(37)->bB

  // ---- last tile 37 (buf1, cur=bB): no staging, no B-next, no barrier ----
  {
    const char* base = smem + 32768;
    WLG0();
    MMX(0, 0, 0, 0, bB); MMX(0, 1, 0, 0, bB); MMX(0, 2, 0, 0, bB); MMX(0, 3, 0, 0, bB);
    af[0][1] = *(const bf16x8*)(base + aoffb[0] + un[1]);
    MMX(1, 0, 0, 0, bB); MMX(1, 1, 0, 0, bB); MMX(1, 2, 0, 0, bB); MMX(1, 3, 0, 0, bB);
    af[1][1] = *(const bf16x8*)(base + aoffb[1] + un[1]);
    MMX(2, 0, 0, 0, bB); MMX(2, 1, 0, 0, bB); MMX(2, 2, 0, 0, bB); MMX(2, 3, 0, 0, bB);
    af[2][1] = *(const bf16x8*)(base + aoffb[2] + un[1]);
    MMX(3, 0, 0, 0, bB); MMX(3, 1, 0, 0, bB); MMX(3, 2, 0, 0, bB); MMX(3, 3, 0, 0, bB);
    af[3][1] = *(const bf16x8*)(base + aoffb[3] + un[1]);
    WLG0();
    MMX(0, 0, 1, 0, bB); MMX(0, 1, 1, 0, bB); MMX(0, 2, 1, 0, bB); MMX(0, 3, 1, 0, bB);
    af[0][0] = *(const bf16x8*)(base + aoffb[4] + un[0]);
    MMX(1, 0, 1, 0, bB); MMX(1, 1, 1, 0, bB); MMX(1, 2, 1, 0, bB); MMX(1, 3, 1, 0, bB);
    af[1][0] = *(const bf16x8*)(base + aoffb[5] + un[0]);
    MMX(2, 0, 1, 0, bB); MMX(2, 1, 1, 0, bB); MMX(2, 2, 1, 0, bB); MMX(2, 3, 1, 0, bB);
    af[2][0] = *(const bf16x8*)(base + aoffb[6] + un[0]);
    MMX(3, 0, 1, 0, bB); MMX(3, 1, 1, 0, bB); MMX(3, 2, 1, 0, bB); MMX(3, 3, 1, 0, bB);
    af[3][0] = *(const bf16x8*)(base + aoffb[7] + un[0]);
    WLG0();
    MMX(0, 0, 0, 4, bB); MMX(0, 1, 0, 4, bB); MMX(0, 2, 0, 4, bB); MMX(0, 3, 0, 4, bB);
    af[0][1] = *(const bf16x8*)(base + aoffb[4] + un[1]);
    MMX(1, 0, 0, 4, bB); MMX(1, 1, 0, 4, bB); MMX(1, 2, 0, 4, bB); MMX(1, 3, 0, 4, bB);
    af[1][1] = *(const bf16x8*)(base + aoffb[5] + un[1]);
    MMX(2, 0, 0, 4, bB); MMX(2, 1, 0, 4, bB); MMX(2, 2, 0, 4, bB); MMX(2, 3, 0, 4, bB);
    af[2][1] = *(const bf16x8*)(base + aoffb[6] + un[1]);
    MMX(3, 0, 0, 4, bB); MMX(3, 1, 0, 4, bB); MMX(3, 2, 0, 4, bB); MMX(3, 3, 0, 4, bB);
    af[3][1] = *(const bf16x8*)(base + aoffb[7] + un[1]);
    WLG0();
    MMX(0, 0, 1, 4, bB); MMX(0, 1, 1, 4, bB); MMX(0, 2, 1, 4, bB); MMX(0, 3, 1, 4, bB);
    MMX(1, 0, 1, 4, bB); MMX(1, 1, 1, 4, bB); MMX(1, 2, 1, 4, bB); MMX(1, 3, 1, 4, bB);
    MMX(2, 0, 1, 4, bB); MMX(2, 1, 1, 4, bB); MMX(2, 2, 1, 4, bB); MMX(2, 3, 1, 4, bB);
    MMX(3, 0, 1, 4, bB); MMX(3, 1, 1, 4, bB); MMX(3, 2, 1, 4, bB); MMX(3, 3, 1, 4, bB);
  }
#undef MMX
#undef TILE_STEADY

  __syncthreads();  // all waves done before epilogue overwrites smem

  // ---- epilogue 1: raw conv -> cv via 64KB LDS repack, two 128-row passes ----
  unsigned short* l16 = (unsigned short*)smem;
#pragma unroll
  for (int p = 0; p < 2; ++p) {
    if (wm == p) {
#pragma unroll
      for (int mf = 0; mf < 8; ++mf)
#pragma unroll
        for (int nf = 0; nf < 4; ++nf)
#pragma unroll
          for (int r = 0; r < 4; ++r) {
            int rowl = mf * 16 + (lane >> 4) * 4 + r;           // local row 0..127
            int col = wn * 64 + nf * 16 + (lane & 15);
            int colx = col ^ (((rowl >> 2) & 3) << 3);
            l16[rowl * 256 + colx] = f2b(acc[mf][nf][r]);
          }
    }
    __syncthreads();
#pragma unroll
    for (int i = 0; i < 8; ++i) {
      int q = tid + 512 * i;                 // 4096 chunks of 16B
      int prow = q >> 5, c16 = q & 31;
      int c16g = c16 ^ ((prow >> 2) & 3);
      *(u16x8*)(cv + ((size_t)(pix0 + p * 128 + prow) * 512 + n0 + c16g * 8)) =
          *(const u16x8*)(l16 + q * 8);
    }
    __syncthreads();
  }

  // ---- epilogue 2: BN partial stats from f32 acc ----
  float* lf = (float*)smem;
  float sv[4], qv[4];
#pragma unroll
  for (int nf = 0; nf < 4; ++nf) {
    float s = 0.f, q = 0.f;
#pragma unroll
    for (int mf = 0; mf < 8; ++mf)
#pragma unroll
      for (int r = 0; r < 4; ++r) { float v = acc[mf][nf][r]; s += v; q += v * v; }
    s += __shfl_xor(s, 16); s += __shfl_xor(s, 32);
    q += __shfl_xor(q, 16); q += __shfl_xor(q, 32);
    sv[nf] = s; qv[nf] = q;
  }
  if (lane < 16) {
#pragma unroll
    for (int nf = 0; nf < 4; ++nf) {
      int ch = wn * 64 + nf * 16 + lane;
      lf[wm * 256 + ch] = sv[nf];
      lf[512 + wm * 256 + ch] = qv[nf];
    }
  }
  __syncthreads();
  if (tid < 256) {
    float S = lf[tid] + lf[256 + tid];
    float Q = lf[512 + tid] + lf[768 + tid];
    ((float2*)ps)[(size_t)(n0 + tid) * 256 + mt] = make_float2(S, Q);
  }
}

// ---------------- BN finalize: scale/bias (16 blocks, shfl-reduced) ----------------
__global__ void k_bnfinal(const float* __restrict__ ps, const float* __restrict__ gamma,
                          const float* __restrict__ beta, float* __restrict__ sb) {
  int c = blockIdx.x * 32 + (threadIdx.x >> 3);
  int sl = threadIdx.x & 7;
  const float2* p2 = (const float2*)ps + (size_t)c * 256 + sl * 32;
  float s = 0.f, q = 0.f;
#pragma unroll 8
  for (int i = 0; i < 32; ++i) { float2 v = p2[i]; s += v.x; q += v.y; }
  s += __shfl_xor(s, 1); s += __shfl_xor(s, 2); s += __shfl_xor(s, 4);
  q += __shfl_xor(q, 1); q += __shfl_xor(q, 2); q += __shfl_xor(q, 4);
  if (sl == 0) {
    float mean = s * (1.0f / 65536.0f);
    float var = q * (1.0f / 65536.0f) - mean * mean;
    float sc = gamma[c] / sqrtf(var + 1e-5f);
    sb[c] = sc;
    sb[512 + c] = beta[c] - mean * sc;
  }
}

// ---------------- head: BN+leaky fused A-load, 256px x 64out GEMM (K=512) + decode ----------------
__global__ __launch_bounds__(256) void k_head(const unsigned short* __restrict__ cv,
                                              const unsigned short* __restrict__ w2,
                                              const float* __restrict__ bl,
                                              const float* __restrict__ bm,
                                              const float* __restrict__ sb,
                                              float* __restrict__ out) {
  __shared__ float lo[256][59];
  __shared__ float sS[512], sBb[512];
  int tid = threadIdx.x, lane = tid & 63, wv = tid >> 6;
  int pix0 = blockIdx.x * 256;
  sS[tid] = sb[tid]; sS[256 + tid] = sb[256 + tid];
  sBb[tid] = sb[512 + tid]; sBb[256 + tid] = sb[768 + tid];
  __syncthreads();

  f32x4 acc[4][4];
#pragma unroll
  for (int mf = 0; mf < 4; ++mf)
#pragma unroll
    for (int nf = 0; nf < 4; ++nf) acc[mf][nf] = (f32x4){0.f, 0.f, 0.f, 0.f};
  int ko = lane >> 4;

  for (int k0 = 0; k0 < 512; k0 += 32) {
    int c0 = k0 + ko * 8;
    f32x4 sc0 = *(const f32x4*)&sS[c0], sc1 = *(const f32x4*)&sS[c0 + 4];
    f32x4 bo0 = *(const f32x4*)&sBb[c0], bo1 = *(const f32x4*)&sBb[c0 + 4];
    bf16x8 a[4], bg[4];
#pragma unroll
    for (int f = 0; f < 4; ++f) {
      bg[f] = *(const bf16x8*)(w2 + (size_t)(f * 16 + (lane & 15)) * 512 + c0);
      u16x8 raw = *(const u16x8*)(cv + (size_t)(pix0 + wv * 64 + f * 16 + (lane & 15)) * 512 + c0);
      u16x8 av;
#pragma unroll
      for (int jj = 0; jj < 4; ++jj) {
        float v = b2f(raw[jj]) * sc0[jj] + bo0[jj];
        v = (v > 0.f) ? v : 0.1f * v;
        av[jj] = f2b(v);
      }
#pragma unroll
      for (int jj = 0; jj < 4; ++jj) {
        float v = b2f(raw[4 + jj]) * sc1[jj] + bo1[jj];
        v = (v > 0.f) ? v : 0.1f * v;
        av[4 + jj] = f2b(v);
      }
      a[f] = __builtin_bit_cast(bf16x8, av);
    }
#pragma unroll
    for (int mf = 0; mf < 4; ++mf)
#pragma unroll
      for (int nf = 0; nf < 4; ++nf)
        acc[mf][nf] = __builtin_amdgcn_mfma_f32_16x16x32_bf16(a[mf], bg[nf], acc[mf][nf], 0, 0, 0);
  }

  float bias[4]; int colv[4];
#pragma unroll
  for (int nf = 0; nf < 4; ++nf) {
    int col = nf * 16 + (lane & 15);
    colv[nf] = col;
    bias[nf] = (col < 10) ? bl[col] : ((col < 58) ? bm[col - 10] : 0.f);
  }
#pragma unroll
  for (int mf = 0; mf < 4; ++mf)
#pragma unroll
    for (int nf = 0; nf < 4; ++nf)
#pragma unroll
      for (int r = 0; r < 4; ++r) {
        int row = wv * 64 + mf * 16 + (lane >> 4) * 4 + r;
        if (colv[nf] < 58) lo[row][colv[nf]] = acc[mf][nf][r] + bias[nf];
      }
  __syncthreads();

  // ---- decode: one thread = one pixel ----
  int pix = pix0 + tid;
  int b = pix >> 12, pi = pix & 4095;
  int yi = pi >> 6, xi = pi & 63;
  float X = (float)xi, Y = (float)yi;
  const float* O = lo[tid];

  float* outP = out;
  float* outB = out + 655360;
  float* outOL = out + 1572864;
  float* outOC = out + 2752512;
  float* outML = out + 3932160;
  float* outMC = out + 4521984;
  float* outWC = out + 5111808;
  float* outOD = out + 5636096;

  float pr[10];
#pragma unroll
  for (int i = 0; i < 10; ++i) { pr[i] = O[i]; outP[(size_t)pix * 10 + i] = pr[i]; }
  const float st = 8.f, ist = 0.125f;
  float l0 = pr[0] * pr[0] * st, l1 = pr[1] * pr[1] * st;
  float l2 = pr[2] * pr[2] * st, l3 = pr[3] * pr[3] * st;
  float cx = X * st + 4.f, cy = Y * st + 4.f;
  float xmin = cx - l3, ymin = cy - l0, xmax = cx + l1, ymax = cy + l2;
  float w = l1 + l3, h = l0 + l2;
  float xc = 0.5f * (xmax + xmin), yc = 0.5f * (ymax + ymin);
  float r = sigf(pr[8]);
  float maskr = (r > 0.9f) ? 0.f : 1.f;
  float s0 = sigf(pr[4]) * maskr, s1 = sigf(pr[5]) * maskr;
  float s2 = sigf(pr[6]) * maskr, s3 = sigf(pr[7]) * maskr;
  float conf = sigf(pr[9]);
  {
    size_t bo = (size_t)pix * 14;
    outB[bo + 0] = xc; outB[bo + 1] = yc; outB[bo + 2] = w; outB[bo + 3] = h;
    outB[bo + 4] = s0; outB[bo + 5] = s1; outB[bo + 6] = s2; outB[bo + 7] = s3;
    outB[bo + 8] = r;  outB[bo + 9] = l0; outB[bo + 10] = l1; outB[bo + 11] = l2;
    outB[bo + 12] = l3; outB[bo + 13] = conf;
  }
  float x1 = xmin + s0 * w, x7 = xmax - s2 * w;
  float y5 = ymin + s1 * h, y3 = ymax - s3 * h;
  float xob = 0.5f * (x1 + x7), yob = 0.5f * (y5 + y3);
  float ov[22];
#pragma unroll
  for (int jj = 0; jj < 22; ++jj) ov[jj] = sigf(O[28 + jj]);
  float eps = ceilf(0.01f * w);
  bool c0 = x1 < xmin + eps;
  float xp0 = c0 ? x1 : xmin + ov[0] * (x1 - xmin);
  float yp0 = c0 ? ymin + ov[0] * (y3 - ymin)
                 : (y3 - ymin) / (xmin - x1 + 1e-8f) * (xp0 - x1) + ymin;
  bool c2 = x1 > xmax - eps;
  float xp2 = c2 ? x1 : xmax - ov[1] * (xmax - x1);
  float yp2 = c2 ? ymin + ov[1] * (y5 - ymin)
                 : (y5 - ymin) / (xmax - x1 + 1e-8f) * (xp2 - x1) + ymin;
  bool c6 = x7 < xmin + eps;
  float xp6 = c6 ? x7 : xmin + ov[2] * (x7 - xmin);
  float yp6 = c6 ? ymax - ov[2] * (ymax - y3)
                 : (y3 - ymax) / (xmin - x7 + 1e-8f) * (xp6 - x7) + ymax;
  bool c8c = x7 > xmax - eps;
  float xp8 = c8c ? x7 : xmax - ov[3] * (xmax - x7);
  float yp8 = c8c ? ymax - ov[3] * (ymax - y5)
                  : (y5 - ymax) / (xmax - x7 + 1e-8f) * (xp8 - x7) + ymax;

  size_t olb = ((size_t)b * 18) * 4096 + pi;
  outOL[olb + 0 * 4096] = yp0 * ist + 1.f - Y;
  outOL[olb + 1 * 4096] = xp0 * ist + 1.f - X;
  outOL[olb + 2 * 4096] = ymin * ist + 1.f - Y;
  outOL[olb + 3 * 4096] = x1 * ist - X;
  outOL[olb + 4 * 4096] = yp2 * ist + 1.f - Y;
  outOL[olb + 5 * 4096] = xp2 * ist - 1.f - X;
  outOL[olb + 6 * 4096] = y3 * ist - Y;
  outOL[olb + 7 * 4096] = xmin * ist + 1.f - X;
  outOL[olb + 8 * 4096] = 0.f;
  outOL[olb + 9 * 4096] = 0.f;
  outOL[olb + 10 * 4096] = y5 * ist - Y;
  outOL[olb + 11 * 4096] = xmax * ist - 1.f - X;
  outOL[olb + 12 * 4096] = yp6 * ist - 1.f - Y;
  outOL[olb + 13 * 4096] = xp6 * ist + 1.f - X;
  outOL[olb + 14 * 4096] = ymax * ist - 1.f - Y;
  outOL[olb + 15 * 4096] = x7 * ist - X;
  outOL[olb + 16 * 4096] = yp8 * ist - 1.f - Y;
  outOL[olb + 17 * 4096] = xp8 * ist - 1.f - X;

  float A1 = x1 - xmax, B1 = ymin - y5, A2 = xmin - x7, B2 = y3 - ymax;
  float width = 0.5f * (sqrtf(A1 * A1 + B1 * B1) + sqrtf(A2 * A2 + B2 * B2));
  float C1 = xmin - x1, D1 = y3 - ymin, C2 = x7 - xmax, D2 = ymax - y5;
  float height = 0.5f * (sqrtf(C1 * C1 + D1 * D1) + sqrtf(C2 * C2 + D2 * D2));
  float ang = 0.5f * (atanf((y5 - ymin) / (xmax - x1 + 1e-4f)) +
                      atanf((ymax - y3) / (x7 - xmin + 1e-4f)));
  float ca = cosf(ang), sa = sinf(ang);
  const float DD = 0.70710678118654752f;
  const float dyc[9] = {DD, 1.f, DD, 0.f, 0.f, 0.f, -DD, -1.f, -DD};
  const float dxc[9] = {DD, 0.f, -DD, 1.f, 0.f, -1.f, DD, 0.f, -DD};
  size_t ocb = ((size_t)b * 18) * 4096 + pi;
  size_t odb = (size_t)pix * 18;
#pragma unroll
  for (int k = 0; k < 9; ++k) {
    float xd = xob - 0.5f * width + ov[13 + k] * width;
    float yd = yob - 0.5f * height + ov[4 + k] * height;
    float ddx = xd - xob, ddy = yd - yob;
    float xd0 = ca * ddx - sa * ddy + xob;
    float xdc = fminf(fmaxf(xd0, xmin), xmax);
    float yd0 = sa * ddx + ca * ddy + yob;
    float ydc = fminf(fmaxf(yd0, ymin), ymax);
    outOC[ocb + (size_t)(2 * k) * 4096] = ydc * ist + dyc[k] - Y;
    outOC[ocb + (size_t)(2 * k + 1) * 4096] = xdc * ist + dxc[k] - X;
    outOD[odb + k] = xdc;
    outOD[odb + 9 + k] = ydc;
  }
  size_t mlb = ((size_t)b * 9) * 4096 + pi;
#pragma unroll
  for (int k = 0; k < 9; ++k) outML[mlb + (size_t)k * 4096] = sigf(O[10 + k]);
#pragma unroll
  for (int k = 0; k < 9; ++k) outMC[mlb + (size_t)k * 4096] = sigf(O[19 + k]);
  float v8[8], mx = -1e30f;
#pragma unroll
  for (int k = 0; k < 8; ++k) { v8[k] = O[50 + k]; mx = fmaxf(mx, v8[k]); }
  float sm = 0.f;
#pragma unroll
  for (int k = 0; k < 8; ++k) { v8[k] = __expf(v8[k] - mx); sm += v8[k]; }
  float inv = 1.f / sm;
  size_t wcb = ((size_t)b * 8) * 4096 + pi;
#pragma unroll
  for (int k = 0; k < 8; ++k) outWC[wcb + (size_t)k * 4096] = v8[k] * inv;
}

// ---------------- launch ----------------
extern "C" void kernel_launch(void* const* d_in, const int* in_sizes, int n_in,
                              void* d_out, int out_size, void* d_ws, size_t ws_size,
                              hipStream_t stream) {
  const float* in1 = (const float*)d_in[0];
  const float* wconv = (const float*)d_in[1];
  const float* gamma = (const float*)d_in[2];
  const float* beta = (const float*)d_in[3];
  const float* wloc = (const float*)d_in[4];
  const float* bloc = (const float*)d_in[5];
  const float* wmask = (const float*)d_in[6];
  const float* bmask = (const float*)d_in[7];
  unsigned char* ws = (unsigned char*)d_ws;
  unsigned short* xp = (unsigned short*)(ws + XP_OFF);
  unsigned short* wt2 = (unsigned short*)(ws + WT_OFF);
  unsigned short* w2 = (unsigned short*)(ws + W2_OFF);
  unsigned short* cv = (unsigned short*)(ws + CV_OFF);
  float* ps = (float*)(ws + PS_OFF);
  float* sb = (float*)(ws + SB_OFF);
  float* out = (float*)d_out;

  (void)hipFuncSetAttribute(reinterpret_cast<const void*>(k_conv8),
                            hipFuncAttributeMaxDynamicSharedMemorySize, 65536);

  k_prep<<<dim3(13977), dim3(256), 0, stream>>>(in1, wconv, wloc, wmask, xp, wt2, w2);
  k_conv8<<<dim3(512), dim3(512), 65536, stream>>>(xp, wt2, cv, ps);
  k_bnfinal<<<dim3(16), dim3(256), 0, stream>>>(ps, gamma, beta, sb);
  k_head<<<dim3(256), dim3(256), 0, stream>>>(cv, w2, bloc, bmask, sb, out);
}